// Round 4
// baseline (768.200 us; speedup 1.0000x reference)
//
#include <hip/hip_runtime.h>

#define DD 128
#define CHUNK 6144      // edges per pass-1 block (LDS staging 48 KB)
#define MAXBK 512       // max coarse buckets (N <= 131072)

typedef _Float16 half8 __attribute__((ext_vector_type(8)));
typedef _Float16 half2v __attribute__((ext_vector_type(2)));
typedef _Float16 half4v __attribute__((ext_vector_type(4)));
typedef float floatx4 __attribute__((ext_vector_type(4)));

// ---------------- CSR row offsets ----------------
__global__ void k_hist(const int* __restrict__ dst, int* __restrict__ counts, int E) {
    int e = blockIdx.x * blockDim.x + threadIdx.x;
    if (e < E) atomicAdd(&counts[dst[e]], 1);
}

__global__ __launch_bounds__(1024) void k_scan_block_sums(const int* __restrict__ counts,
                                                          int* __restrict__ blockSums, int N) {
    __shared__ int s[1024];
    int t = threadIdx.x;
    int idx = blockIdx.x * 1024 + t;
    s[t] = (idx < N) ? counts[idx] : 0;
    __syncthreads();
    for (int off = 512; off > 0; off >>= 1) {
        if (t < off) s[t] += s[t + off];
        __syncthreads();
    }
    if (t == 0) blockSums[blockIdx.x] = s[0];
}

__global__ __launch_bounds__(1024) void k_scan_offsets(const int* __restrict__ blockSums,
                                                       int* __restrict__ blockOffs, int nb,
                                                       int* __restrict__ row_end) {
    __shared__ int s[1024];
    int t = threadIdx.x;
    int v = (t < nb) ? blockSums[t] : 0;
    s[t] = v;
    __syncthreads();
    for (int off = 1; off < 1024; off <<= 1) {
        int x = (t >= off) ? s[t - off] : 0;
        __syncthreads();
        s[t] += x;
        __syncthreads();
    }
    if (t < nb) blockOffs[t] = s[t] - v;
    if (t == 1023) *row_end = s[t];
}

__global__ __launch_bounds__(1024) void k_scan_final(const int* __restrict__ counts,
                                                     const int* __restrict__ blockOffs,
                                                     int* __restrict__ row_start,
                                                     int* __restrict__ cursor, int N) {
    __shared__ int s[1024];
    int t = threadIdx.x;
    int idx = blockIdx.x * 1024 + t;
    int v = (idx < N) ? counts[idx] : 0;
    s[t] = v;
    __syncthreads();
    for (int off = 1; off < 1024; off <<= 1) {
        int x = (t >= off) ? s[t - off] : 0;
        __syncthreads();
        s[t] += x;
        __syncthreads();
    }
    int excl = s[t] - v + blockOffs[blockIdx.x];
    if (idx < N) { row_start[idx] = excl; cursor[idx] = excl; }
}

// ---------------- pass 1: block-local binning into coarse buckets ----------------
// bucket = dst >> 8 (256 dst nodes per bucket). Output: edges grouped by bucket,
// packed rec = { src | (dst&255)<<24 , w_bits }  (src < 2^24 assumed).
__global__ __launch_bounds__(256) void k_pass1(const int* __restrict__ src,
                                               const int* __restrict__ dst,
                                               const float* __restrict__ w,
                                               const int* __restrict__ row_start,
                                               int* __restrict__ gcur,
                                               int2* __restrict__ out, int E, int NB) {
    __shared__ int2 stg[CHUNK];
    __shared__ int lhist[MAXBK];
    __shared__ int loff[MAXBK];
    __shared__ int lcur[MAXBK];
    int tid = threadIdx.x;
    int beg = blockIdx.x * CHUNK;
    int end = min(beg + CHUNK, E);

    for (int b = tid; b < MAXBK; b += 256) lhist[b] = 0;
    __syncthreads();
    // phase A: histogram
    for (int k = beg + tid; k < end; k += 256)
        atomicAdd(&lhist[dst[k] >> 8], 1);
    __syncthreads();
    // phase B: exclusive scan (single wave: 8 entries/lane + wave scan)
    if (tid < 64) {
        int base = tid * 8, v[8], s = 0;
        #pragma unroll
        for (int j = 0; j < 8; ++j) { v[j] = lhist[base + j]; s += v[j]; }
        int sc = s;
        #pragma unroll
        for (int off = 1; off < 64; off <<= 1) {
            int t = __shfl_up(sc, off, 64);
            if (tid >= off) sc += t;
        }
        int excl = sc - s;
        #pragma unroll
        for (int j = 0; j < 8; ++j) {
            loff[base + j] = excl; lcur[base + j] = excl; excl += v[j];
        }
    }
    __syncthreads();
    // phase C: scatter into LDS staging grouped by bucket
    for (int k = beg + tid; k < end; k += 256) {
        int d = dst[k];
        int b = d >> 8;
        int p = atomicAdd(&lcur[b], 1);
        stg[p] = make_int2(src[k] | ((d & 255) << 24), __float_as_int(w[k]));
    }
    __syncthreads();
    // phase D: bulk-reserve + contiguous run write per bucket
    int wave = tid >> 6, lane = tid & 63;
    for (int b = wave; b < NB; b += 4) {
        int cnt = lhist[b];
        if (cnt == 0) continue;
        int base;
        if (lane == 0) base = atomicAdd(&gcur[b], cnt);
        base = __shfl(base, 0, 64);
        int gb = row_start[b << 8] + base;
        int lb = loff[b];
        for (int j = lane; j < cnt; j += 64)
            out[gb + j] = stg[lb + j];
    }
}

// ---------------- pass 2: fine sort within bucket (writes L2-local) ----------------
__global__ __launch_bounds__(256) void k_pass2(const int2* __restrict__ bkt,
                                               const int* __restrict__ row_start,
                                               int* __restrict__ cursor,
                                               int2* __restrict__ edges, int N) {
    int b = blockIdx.x;
    int d0 = b << 8;
    int d1 = min(d0 + 256, N);
    int sb = row_start[d0], se = row_start[d1];
    for (int i = sb + threadIdx.x; i < se; i += 256) {
        int2 r = bkt[i];
        int d = d0 + ((unsigned)r.x >> 24);
        int p = atomicAdd(&cursor[d], 1);
        edges[p] = make_int2(r.x & 0xFFFFFF, r.y);
    }
}

// ---------------- casts ----------------
__global__ void k_cast_f2h(const float* __restrict__ in, _Float16* __restrict__ out, int n4) {
    int i = blockIdx.x * blockDim.x + threadIdx.x;
    if (i >= n4) return;
    float4 v = reinterpret_cast<const float4*>(in)[i];
    half4v h;
    h.x = (_Float16)v.x; h.y = (_Float16)v.y; h.z = (_Float16)v.z; h.w = (_Float16)v.w;
    reinterpret_cast<half4v*>(out)[i] = h;
}

__global__ void k_cast_wT(const float* __restrict__ W, _Float16* __restrict__ Wt) {
    int idx = blockIdx.x * blockDim.x + threadIdx.x;
    int n = idx >> 7, k = idx & 127;
    Wt[n * DD + k] = (_Float16)W[k * DD + n];
}

// ---------------- aggregation: one wave per dst; 16 lanes/row, 4 rows per gather ----
__global__ __launch_bounds__(256) void k_aggregate_h(const _Float16* __restrict__ x,
                                                     const int* __restrict__ row_start,
                                                     const int2* __restrict__ edges,
                                                     _Float16* __restrict__ out, int N) {
    int wid = (blockIdx.x * blockDim.x + threadIdx.x) >> 6;
    int lane = threadIdx.x & 63;
    if (wid >= N) return;
    int g = lane >> 4;    // edge group 0..3
    int sl = lane & 15;   // 16B chunk: cols sl*8 .. sl*8+7
    int beg = row_start[wid], end = row_start[wid + 1];
    float acc[8] = {0.f, 0.f, 0.f, 0.f, 0.f, 0.f, 0.f, 0.f};
    int i = beg;
    for (; i + 16 <= end; i += 16) {
        int2 e[4];
        #pragma unroll
        for (int u = 0; u < 4; ++u) e[u] = edges[i + u * 4 + g];
        half8 v[4];
        #pragma unroll
        for (int u = 0; u < 4; ++u)
            v[u] = *reinterpret_cast<const half8*>(x + (size_t)e[u].x * DD + sl * 8);
        #pragma unroll
        for (int u = 0; u < 4; ++u) {
            float wv = __int_as_float(e[u].y);
            #pragma unroll
            for (int j = 0; j < 8; ++j)
                acc[j] = fmaf((float)v[u][j], wv, acc[j]);
        }
    }
    for (; i < end; i += 4) {
        int rem = end - i;                 // >= 1
        int2 e = edges[i + min(g, rem - 1)];
        half8 v = *reinterpret_cast<const half8*>(x + (size_t)e.x * DD + sl * 8);
        float wv = (g < rem) ? __int_as_float(e.y) : 0.f;
        #pragma unroll
        for (int j = 0; j < 8; ++j)
            acc[j] = fmaf((float)v[j], wv, acc[j]);
    }
    // reduce across the 4 edge groups (lanes l, l+16, l+32, l+48 share cols)
    #pragma unroll
    for (int j = 0; j < 8; ++j) {
        acc[j] += __shfl_xor(acc[j], 16, 64);
        acc[j] += __shfl_xor(acc[j], 32, 64);
    }
    if (g == 0) {
        half8 o;
        #pragma unroll
        for (int j = 0; j < 8; ++j) o[j] = (_Float16)acc[j];
        *reinterpret_cast<half8*>(out + (size_t)wid * DD + sl * 8) = o;
    }
}

// ---------------- MFMA GEMM: out = relu(A @ W + b) [+ resid], LDS-free ----------
__global__ __launch_bounds__(256) void k_gemm_mfma(const _Float16* __restrict__ A,
                                                   const _Float16* __restrict__ Wt,
                                                   const float* __restrict__ bias,
                                                   const _Float16* __restrict__ resid_h,
                                                   float* __restrict__ out_f32,
                                                   _Float16* __restrict__ out_f16,
                                                   int nrows) {
    int wave = threadIdx.x >> 6;
    int lane = threadIdx.x & 63;
    int row0 = blockIdx.x * 128 + wave * 32;
    int m = lane & 15;
    int q = lane >> 4;

    floatx4 acc[2][8];
    #pragma unroll
    for (int t = 0; t < 2; ++t)
        #pragma unroll
        for (int c = 0; c < 8; ++c)
            acc[t][c] = (floatx4){0.f, 0.f, 0.f, 0.f};

    #pragma unroll
    for (int ks = 0; ks < 4; ++ks) {
        int kbase = ks * 32 + q * 8;
        half8 a0 = *reinterpret_cast<const half8*>(A + (size_t)(row0 + m) * DD + kbase);
        half8 a1 = *reinterpret_cast<const half8*>(A + (size_t)(row0 + 16 + m) * DD + kbase);
        #pragma unroll
        for (int c = 0; c < 8; ++c) {
            half8 b = *reinterpret_cast<const half8*>(Wt + (size_t)(c * 16 + m) * DD + kbase);
            acc[0][c] = __builtin_amdgcn_mfma_f32_16x16x32_f16(a0, b, acc[0][c], 0, 0, 0);
            acc[1][c] = __builtin_amdgcn_mfma_f32_16x16x32_f16(a1, b, acc[1][c], 0, 0, 0);
        }
    }

    #pragma unroll
    for (int t = 0; t < 2; ++t) {
        #pragma unroll
        for (int c = 0; c < 8; ++c) {
            int col = c * 16 + m;
            float bv = bias[col];
            #pragma unroll
            for (int r = 0; r < 4; ++r) {
                int row = row0 + t * 16 + q * 4 + r;
                if (row < nrows) {
                    float v = acc[t][c][r] + bv;
                    v = v > 0.f ? v : 0.f;
                    if (resid_h) v += (float)resid_h[(size_t)row * DD + col];
                    if (out_f32) out_f32[(size_t)row * DD + col] = v;
                    if (out_f16) out_f16[(size_t)row * DD + col] = (_Float16)v;
                }
            }
        }
    }
}

// ---------------- per-subgraph mean pool + target residual ----------------
__global__ __launch_bounds__(128) void k_pool(const float* __restrict__ h,
                                              const int* __restrict__ target,
                                              const float* __restrict__ size_subg,
                                              float* __restrict__ pooled, int SZ) {
    int b = blockIdx.x;
    int d = threadIdx.x;
    const float* hp = h + (size_t)b * SZ * DD;
    float s = 0.f;
    for (int n = 0; n < SZ; ++n) s += hp[(size_t)n * DD + d];
    int t = target[b];
    float p = s / size_subg[b] + h[(size_t)t * DD + d];
    pooled[b * DD + d] = p;
}

// ---------------- final: relu(pooled @ Wp + bp), L2-normalize rows ----------------
__global__ __launch_bounds__(128) void k_final(const float* __restrict__ pooled,
                                               const float* __restrict__ Wp,
                                               const float* __restrict__ bp,
                                               float* __restrict__ out) {
    __shared__ float p[DD];
    __shared__ float wsum[2];
    int b = blockIdx.x;
    int c = threadIdx.x;
    p[c] = pooled[b * DD + c];
    __syncthreads();
    float acc = 0.f;
    #pragma unroll 4
    for (int k = 0; k < DD; ++k) acc = fmaf(p[k], Wp[k * DD + c], acc);
    float e = acc + bp[c];
    e = e > 0.f ? e : 0.f;
    float sq = e * e;
    #pragma unroll
    for (int off = 32; off > 0; off >>= 1) sq += __shfl_down(sq, off, 64);
    int lane = c & 63, w = c >> 6;
    if (lane == 0) wsum[w] = sq;
    __syncthreads();
    float norm = sqrtf(wsum[0] + wsum[1]);
    float scale = 1.f / fmaxf(norm, 1e-12f);
    out[b * DD + c] = e * scale;
}

extern "C" void kernel_launch(void* const* d_in, const int* in_sizes, int n_in,
                              void* d_out, int out_size, void* d_ws, size_t ws_size,
                              hipStream_t stream) {
    const float* feat      = (const float*)d_in[0];
    const float* edge_w    = (const float*)d_in[1];
    const float* W1        = (const float*)d_in[2];
    const float* b1        = (const float*)d_in[3];
    const float* W2        = (const float*)d_in[4];
    const float* b2        = (const float*)d_in[5];
    const float* Wp        = (const float*)d_in[6];
    const float* bp        = (const float*)d_in[7];
    const float* size_subg = (const float*)d_in[8];
    const int*   edge_src  = (const int*)d_in[9];
    const int*   edge_dst  = (const int*)d_in[10];
    const int*   target    = (const int*)d_in[12];

    const int N  = in_sizes[0] / DD;
    const int E  = in_sizes[1];
    const int B  = in_sizes[8];
    const int SZ = N / B;

    const int gemmBlocks = (N + 127) / 128;
    const int P = gemmBlocks * 128;
    const int NB = (N + 255) >> 8;          // coarse buckets

    char* ws = (char*)d_ws;
    size_t off = 0;
    auto alloc = [&](size_t bytes) {
        void* p = ws + off;
        off += (bytes + 255) & ~(size_t)255;
        return p;
    };
    // region0: feat_h + agg1_h overlay; later reused as fp32 H
    char* region0   = (char*)alloc((size_t)N * DD * 4 + 40 * 1024);
    _Float16* feat_h = (_Float16*)region0;
    _Float16* agg1_h = (_Float16*)(region0 + (size_t)N * DD * 2);
    float*    H      = (float*)region0;
    _Float16* h1_h   = (_Float16*)alloc((size_t)P * DD * 2);
    _Float16* agg2_h = (_Float16*)alloc((size_t)P * DD * 2);  // also edges_bkt (pass1 out)
    int2*     edges_bkt = (int2*)agg2_h;                      // dead before agg2 is written
    _Float16* W1t    = (_Float16*)alloc((size_t)DD * DD * 2);
    _Float16* W2t    = (_Float16*)alloc((size_t)DD * DD * 2);
    int*   counts    = (int*)alloc((size_t)N * 4);
    int*   row_start = (int*)alloc(((size_t)N + 1) * 4);
    int*   cursor    = (int*)alloc((size_t)N * 4);
    int nb = (N + 1023) / 1024;
    int*   blockSums = (int*)alloc((size_t)nb * 4);
    int*   blockOffs = (int*)alloc((size_t)nb * 4);
    int*   gcur      = (int*)alloc((size_t)MAXBK * 4);
    int2*  edges     = (int2*)alloc((size_t)E * 8);
    float* pooled    = (float*)alloc((size_t)B * DD * 4);

    // ---- CSR row offsets ----
    hipMemsetAsync(counts, 0, (size_t)N * 4, stream);
    hipMemsetAsync(gcur, 0, (size_t)MAXBK * 4, stream);
    k_hist<<<(E + 255) / 256, 256, 0, stream>>>(edge_dst, counts, E);
    k_scan_block_sums<<<nb, 1024, 0, stream>>>(counts, blockSums, N);
    k_scan_offsets<<<1, 1024, 0, stream>>>(blockSums, blockOffs, nb, row_start + N);
    k_scan_final<<<nb, 1024, 0, stream>>>(counts, blockOffs, row_start, cursor, N);

    // ---- two-pass edge placement ----
    int p1Blocks = (E + CHUNK - 1) / CHUNK;
    k_pass1<<<p1Blocks, 256, 0, stream>>>(edge_src, edge_dst, edge_w, row_start,
                                          gcur, edges_bkt, E, NB);
    k_pass2<<<NB, 256, 0, stream>>>(edges_bkt, row_start, cursor, edges, N);

    // ---- casts ----
    int n4 = N * DD / 4;
    k_cast_f2h<<<(n4 + 255) / 256, 256, 0, stream>>>(feat, feat_h, n4);
    k_cast_wT<<<64, 256, 0, stream>>>(W1, W1t);
    k_cast_wT<<<64, 256, 0, stream>>>(W2, W2t);

    int aggBlocks = (N * 64 + 255) / 256;   // one wave per node

    // layer 1
    k_aggregate_h<<<aggBlocks, 256, 0, stream>>>(feat_h, row_start, edges, agg1_h, N);
    k_gemm_mfma<<<gemmBlocks, 256, 0, stream>>>(agg1_h, W1t, b1, nullptr,
                                                nullptr, h1_h, N);
    // layer 2
    k_aggregate_h<<<aggBlocks, 256, 0, stream>>>(h1_h, row_start, edges, agg2_h, N);
    k_gemm_mfma<<<gemmBlocks, 256, 0, stream>>>(agg2_h, W2t, b2, h1_h,
                                                H, nullptr, N);
    // pool + final
    k_pool<<<B, 128, 0, stream>>>(H, target, size_subg, pooled, SZ);
    k_final<<<B, 128, 0, stream>>>(pooled, Wp, bp, (float*)d_out);
}

// Round 5
// 542.168 us; speedup vs baseline: 1.4169x; 1.4169x over previous
//
#include <hip/hip_runtime.h>

#define DD 128
#define CHUNK 4096      // edges per pass-1 block
#define BSH 9           // bucket = dst >> 9  (512 nodes/bucket)
#define MAXBK 256       // max coarse buckets (N <= 131072)

typedef _Float16 half8 __attribute__((ext_vector_type(8)));
typedef _Float16 half2v __attribute__((ext_vector_type(2)));
typedef _Float16 half4v __attribute__((ext_vector_type(4)));
typedef float floatx4 __attribute__((ext_vector_type(4)));

// ---------------- CSR row offsets ----------------
__global__ void k_hist(const int* __restrict__ dst, int* __restrict__ counts, int E) {
    int e = blockIdx.x * blockDim.x + threadIdx.x;
    if (e < E) atomicAdd(&counts[dst[e]], 1);
}

__global__ __launch_bounds__(1024) void k_scan_block_sums(const int* __restrict__ counts,
                                                          int* __restrict__ blockSums, int N) {
    __shared__ int s[1024];
    int t = threadIdx.x;
    int idx = blockIdx.x * 1024 + t;
    s[t] = (idx < N) ? counts[idx] : 0;
    __syncthreads();
    for (int off = 512; off > 0; off >>= 1) {
        if (t < off) s[t] += s[t + off];
        __syncthreads();
    }
    if (t == 0) blockSums[blockIdx.x] = s[0];
}

__global__ __launch_bounds__(1024) void k_scan_offsets(const int* __restrict__ blockSums,
                                                       int* __restrict__ blockOffs, int nb,
                                                       int* __restrict__ row_end) {
    __shared__ int s[1024];
    int t = threadIdx.x;
    int v = (t < nb) ? blockSums[t] : 0;
    s[t] = v;
    __syncthreads();
    for (int off = 1; off < 1024; off <<= 1) {
        int x = (t >= off) ? s[t - off] : 0;
        __syncthreads();
        s[t] += x;
        __syncthreads();
    }
    if (t < nb) blockOffs[t] = s[t] - v;
    if (t == 1023) *row_end = s[t];
}

__global__ __launch_bounds__(1024) void k_scan_final(const int* __restrict__ counts,
                                                     const int* __restrict__ blockOffs,
                                                     int* __restrict__ row_start,
                                                     int* __restrict__ cursor, int N) {
    __shared__ int s[1024];
    int t = threadIdx.x;
    int idx = blockIdx.x * 1024 + t;
    int v = (idx < N) ? counts[idx] : 0;
    s[t] = v;
    __syncthreads();
    for (int off = 1; off < 1024; off <<= 1) {
        int x = (t >= off) ? s[t - off] : 0;
        __syncthreads();
        s[t] += x;
        __syncthreads();
    }
    int excl = s[t] - v + blockOffs[blockIdx.x];
    if (idx < N) { row_start[idx] = excl; cursor[idx] = excl; }
}

// ---------------- pass 1: bucket-bin edges, direct global run-writes ----------------
// bucket = dst >> BSH. Each block reserves one contiguous run per bucket and
// streams records straight to global (run ≈ CHUNK/NB edges ≈ 168 B → full lines).
// rec = { src | dlocal<<17 , w_bits }   (requires N <= 2^17)
__global__ __launch_bounds__(256) void k_pass1(const int* __restrict__ src,
                                               const int* __restrict__ dst,
                                               const float* __restrict__ w,
                                               const int* __restrict__ row_start,
                                               int* __restrict__ gcur,
                                               int2* __restrict__ out, int E, int NB) {
    __shared__ int lhist[MAXBK];
    __shared__ int lbase[MAXBK];
    __shared__ int lcur[MAXBK];
    int tid = threadIdx.x;
    int beg = blockIdx.x * CHUNK;
    int end = min(beg + CHUNK, E);

    lhist[tid] = 0;
    lcur[tid] = 0;
    __syncthreads();
    // phase A: histogram of this chunk
    for (int k = beg + tid; k < end; k += 256)
        atomicAdd(&lhist[dst[k] >> BSH], 1);
    __syncthreads();
    // phase B: bulk-reserve a run in each bucket
    if (tid < NB) {
        int c = lhist[tid];
        int base = 0;
        if (c) base = atomicAdd(&gcur[tid], c);
        lbase[tid] = row_start[tid << BSH] + base;
    }
    __syncthreads();
    // phase C: direct write into the reserved runs
    for (int k = beg + tid; k < end; k += 256) {
        int d = dst[k];
        int b = d >> BSH;
        int loc = atomicAdd(&lcur[b], 1);
        out[lbase[b] + loc] =
            make_int2(src[k] | ((d & ((1 << BSH) - 1)) << 17), __float_as_int(w[k]));
    }
}

// ---------------- pass 2: fine sort within bucket (writes L2-local) ----------------
__global__ __launch_bounds__(256) void k_pass2(const int2* __restrict__ bkt,
                                               const int* __restrict__ row_start,
                                               int* __restrict__ cursor,
                                               int2* __restrict__ edges, int N) {
    int b = blockIdx.x;
    int d0 = b << BSH;
    int d1 = min(d0 + (1 << BSH), N);
    int sb = row_start[d0], se = row_start[d1];
    for (int i = sb + threadIdx.x; i < se; i += 256) {
        int2 r = bkt[i];
        int d = d0 + ((unsigned)r.x >> 17);
        int p = atomicAdd(&cursor[d], 1);
        edges[p] = make_int2(r.x & 0x1FFFF, r.y);
    }
}

// ---------------- casts ----------------
__global__ void k_cast_f2h(const float* __restrict__ in, _Float16* __restrict__ out, int n4) {
    int i = blockIdx.x * blockDim.x + threadIdx.x;
    if (i >= n4) return;
    float4 v = reinterpret_cast<const float4*>(in)[i];
    half4v h;
    h.x = (_Float16)v.x; h.y = (_Float16)v.y; h.z = (_Float16)v.z; h.w = (_Float16)v.w;
    reinterpret_cast<half4v*>(out)[i] = h;
}

__global__ void k_cast_wT(const float* __restrict__ W, _Float16* __restrict__ Wt) {
    int idx = blockIdx.x * blockDim.x + threadIdx.x;
    int n = idx >> 7, k = idx & 127;
    Wt[n * DD + k] = (_Float16)W[k * DD + n];
}

// ---------------- aggregation: one wave per dst; 16 lanes/row, 4 rows per gather ----
__global__ __launch_bounds__(256) void k_aggregate_h(const _Float16* __restrict__ x,
                                                     const int* __restrict__ row_start,
                                                     const int2* __restrict__ edges,
                                                     _Float16* __restrict__ out, int N) {
    int wid = (blockIdx.x * blockDim.x + threadIdx.x) >> 6;
    int lane = threadIdx.x & 63;
    if (wid >= N) return;
    int g = lane >> 4;    // edge group 0..3
    int sl = lane & 15;   // 16B chunk: cols sl*8 .. sl*8+7
    int beg = row_start[wid], end = row_start[wid + 1];
    float acc[8] = {0.f, 0.f, 0.f, 0.f, 0.f, 0.f, 0.f, 0.f};
    int i = beg;
    for (; i + 16 <= end; i += 16) {
        int2 e[4];
        #pragma unroll
        for (int u = 0; u < 4; ++u) e[u] = edges[i + u * 4 + g];
        half8 v[4];
        #pragma unroll
        for (int u = 0; u < 4; ++u)
            v[u] = *reinterpret_cast<const half8*>(x + (size_t)e[u].x * DD + sl * 8);
        #pragma unroll
        for (int u = 0; u < 4; ++u) {
            float wv = __int_as_float(e[u].y);
            #pragma unroll
            for (int j = 0; j < 8; ++j)
                acc[j] = fmaf((float)v[u][j], wv, acc[j]);
        }
    }
    for (; i < end; i += 4) {
        int rem = end - i;                 // >= 1
        int2 e = edges[i + min(g, rem - 1)];
        half8 v = *reinterpret_cast<const half8*>(x + (size_t)e.x * DD + sl * 8);
        float wv = (g < rem) ? __int_as_float(e.y) : 0.f;
        #pragma unroll
        for (int j = 0; j < 8; ++j)
            acc[j] = fmaf((float)v[j], wv, acc[j]);
    }
    #pragma unroll
    for (int j = 0; j < 8; ++j) {
        acc[j] += __shfl_xor(acc[j], 16, 64);
        acc[j] += __shfl_xor(acc[j], 32, 64);
    }
    if (g == 0) {
        half8 o;
        #pragma unroll
        for (int j = 0; j < 8; ++j) o[j] = (_Float16)acc[j];
        *reinterpret_cast<half8*>(out + (size_t)wid * DD + sl * 8) = o;
    }
}

// ---------------- MFMA GEMM: out = relu(A @ W + b) [+ resid], LDS-free ----------
__global__ __launch_bounds__(256) void k_gemm_mfma(const _Float16* __restrict__ A,
                                                   const _Float16* __restrict__ Wt,
                                                   const float* __restrict__ bias,
                                                   const _Float16* __restrict__ resid_h,
                                                   float* __restrict__ out_f32,
                                                   _Float16* __restrict__ out_f16,
                                                   int nrows) {
    int wave = threadIdx.x >> 6;
    int lane = threadIdx.x & 63;
    int row0 = blockIdx.x * 128 + wave * 32;
    int m = lane & 15;
    int q = lane >> 4;

    floatx4 acc[2][8];
    #pragma unroll
    for (int t = 0; t < 2; ++t)
        #pragma unroll
        for (int c = 0; c < 8; ++c)
            acc[t][c] = (floatx4){0.f, 0.f, 0.f, 0.f};

    #pragma unroll
    for (int ks = 0; ks < 4; ++ks) {
        int kbase = ks * 32 + q * 8;
        half8 a0 = *reinterpret_cast<const half8*>(A + (size_t)(row0 + m) * DD + kbase);
        half8 a1 = *reinterpret_cast<const half8*>(A + (size_t)(row0 + 16 + m) * DD + kbase);
        #pragma unroll
        for (int c = 0; c < 8; ++c) {
            half8 b = *reinterpret_cast<const half8*>(Wt + (size_t)(c * 16 + m) * DD + kbase);
            acc[0][c] = __builtin_amdgcn_mfma_f32_16x16x32_f16(a0, b, acc[0][c], 0, 0, 0);
            acc[1][c] = __builtin_amdgcn_mfma_f32_16x16x32_f16(a1, b, acc[1][c], 0, 0, 0);
        }
    }

    #pragma unroll
    for (int t = 0; t < 2; ++t) {
        #pragma unroll
        for (int c = 0; c < 8; ++c) {
            int col = c * 16 + m;
            float bv = bias[col];
            #pragma unroll
            for (int r = 0; r < 4; ++r) {
                int row = row0 + t * 16 + q * 4 + r;
                if (row < nrows) {
                    float v = acc[t][c][r] + bv;
                    v = v > 0.f ? v : 0.f;
                    if (resid_h) v += (float)resid_h[(size_t)row * DD + col];
                    if (out_f32) out_f32[(size_t)row * DD + col] = v;
                    if (out_f16) out_f16[(size_t)row * DD + col] = (_Float16)v;
                }
            }
        }
    }
}

// ---------------- per-subgraph mean pool + target residual ----------------
__global__ __launch_bounds__(128) void k_pool(const float* __restrict__ h,
                                              const int* __restrict__ target,
                                              const float* __restrict__ size_subg,
                                              float* __restrict__ pooled, int SZ) {
    int b = blockIdx.x;
    int d = threadIdx.x;
    const float* hp = h + (size_t)b * SZ * DD;
    float s = 0.f;
    for (int n = 0; n < SZ; ++n) s += hp[(size_t)n * DD + d];
    int t = target[b];
    float p = s / size_subg[b] + h[(size_t)t * DD + d];
    pooled[b * DD + d] = p;
}

// ---------------- final: relu(pooled @ Wp + bp), L2-normalize rows ----------------
__global__ __launch_bounds__(128) void k_final(const float* __restrict__ pooled,
                                               const float* __restrict__ Wp,
                                               const float* __restrict__ bp,
                                               float* __restrict__ out) {
    __shared__ float p[DD];
    __shared__ float wsum[2];
    int b = blockIdx.x;
    int c = threadIdx.x;
    p[c] = pooled[b * DD + c];
    __syncthreads();
    float acc = 0.f;
    #pragma unroll 4
    for (int k = 0; k < DD; ++k) acc = fmaf(p[k], Wp[k * DD + c], acc);
    float e = acc + bp[c];
    e = e > 0.f ? e : 0.f;
    float sq = e * e;
    #pragma unroll
    for (int off = 32; off > 0; off >>= 1) sq += __shfl_down(sq, off, 64);
    int lane = c & 63, w = c >> 6;
    if (lane == 0) wsum[w] = sq;
    __syncthreads();
    float norm = sqrtf(wsum[0] + wsum[1]);
    float scale = 1.f / fmaxf(norm, 1e-12f);
    out[b * DD + c] = e * scale;
}

extern "C" void kernel_launch(void* const* d_in, const int* in_sizes, int n_in,
                              void* d_out, int out_size, void* d_ws, size_t ws_size,
                              hipStream_t stream) {
    const float* feat      = (const float*)d_in[0];
    const float* edge_w    = (const float*)d_in[1];
    const float* W1        = (const float*)d_in[2];
    const float* b1        = (const float*)d_in[3];
    const float* W2        = (const float*)d_in[4];
    const float* b2        = (const float*)d_in[5];
    const float* Wp        = (const float*)d_in[6];
    const float* bp        = (const float*)d_in[7];
    const float* size_subg = (const float*)d_in[8];
    const int*   edge_src  = (const int*)d_in[9];
    const int*   edge_dst  = (const int*)d_in[10];
    const int*   target    = (const int*)d_in[12];

    const int N  = in_sizes[0] / DD;
    const int E  = in_sizes[1];
    const int B  = in_sizes[8];
    const int SZ = N / B;

    const int gemmBlocks = (N + 127) / 128;
    const int P = gemmBlocks * 128;
    const int NB = (N + (1 << BSH) - 1) >> BSH;   // coarse buckets

    char* ws = (char*)d_ws;
    size_t off = 0;
    auto alloc = [&](size_t bytes) {
        void* p = ws + off;
        off += (bytes + 255) & ~(size_t)255;
        return p;
    };
    // region0: feat_h + agg1_h overlay; later reused as fp32 H
    char* region0   = (char*)alloc((size_t)N * DD * 4 + 40 * 1024);
    _Float16* feat_h = (_Float16*)region0;
    _Float16* agg1_h = (_Float16*)(region0 + (size_t)N * DD * 2);
    float*    H      = (float*)region0;
    _Float16* h1_h   = (_Float16*)alloc((size_t)P * DD * 2);
    _Float16* agg2_h = (_Float16*)alloc((size_t)P * DD * 2);  // also edges_bkt (pass1 out)
    int2*     edges_bkt = (int2*)agg2_h;                      // dead before agg2 is written
    _Float16* W1t    = (_Float16*)alloc((size_t)DD * DD * 2);
    _Float16* W2t    = (_Float16*)alloc((size_t)DD * DD * 2);
    int*   counts    = (int*)alloc((size_t)N * 4);
    int*   row_start = (int*)alloc(((size_t)N + 1) * 4);
    int*   cursor    = (int*)alloc((size_t)N * 4);
    int nb = (N + 1023) / 1024;
    int*   blockSums = (int*)alloc((size_t)nb * 4);
    int*   blockOffs = (int*)alloc((size_t)nb * 4);
    int*   gcur      = (int*)alloc((size_t)MAXBK * 4);
    int2*  edges     = (int2*)alloc((size_t)E * 8);
    float* pooled    = (float*)alloc((size_t)B * DD * 4);

    // ---- CSR row offsets ----
    hipMemsetAsync(counts, 0, (size_t)N * 4, stream);
    hipMemsetAsync(gcur, 0, (size_t)MAXBK * 4, stream);
    k_hist<<<(E + 255) / 256, 256, 0, stream>>>(edge_dst, counts, E);
    k_scan_block_sums<<<nb, 1024, 0, stream>>>(counts, blockSums, N);
    k_scan_offsets<<<1, 1024, 0, stream>>>(blockSums, blockOffs, nb, row_start + N);
    k_scan_final<<<nb, 1024, 0, stream>>>(counts, blockOffs, row_start, cursor, N);

    // ---- two-pass edge placement ----
    int p1Blocks = (E + CHUNK - 1) / CHUNK;
    k_pass1<<<p1Blocks, 256, 0, stream>>>(edge_src, edge_dst, edge_w, row_start,
                                          gcur, edges_bkt, E, NB);
    k_pass2<<<NB, 256, 0, stream>>>(edges_bkt, row_start, cursor, edges, N);

    // ---- casts ----
    int n4 = N * DD / 4;
    k_cast_f2h<<<(n4 + 255) / 256, 256, 0, stream>>>(feat, feat_h, n4);
    k_cast_wT<<<64, 256, 0, stream>>>(W1, W1t);
    k_cast_wT<<<64, 256, 0, stream>>>(W2, W2t);

    int aggBlocks = (N * 64 + 255) / 256;   // one wave per node

    // layer 1
    k_aggregate_h<<<aggBlocks, 256, 0, stream>>>(feat_h, row_start, edges, agg1_h, N);
    k_gemm_mfma<<<gemmBlocks, 256, 0, stream>>>(agg1_h, W1t, b1, nullptr,
                                                nullptr, h1_h, N);
    // layer 2
    k_aggregate_h<<<aggBlocks, 256, 0, stream>>>(h1_h, row_start, edges, agg2_h, N);
    k_gemm_mfma<<<gemmBlocks, 256, 0, stream>>>(agg2_h, W2t, b2, h1_h,
                                                H, nullptr, N);
    // pool + final
    k_pool<<<B, 128, 0, stream>>>(H, target, size_subg, pooled, SZ);
    k_final<<<B, 128, 0, stream>>>(pooled, Wp, bp, (float*)d_out);
}

// Round 6
// 458.002 us; speedup vs baseline: 1.6773x; 1.1838x over previous
//
#include <hip/hip_runtime.h>

#define DD 128
#define CHUNK 4096      // edges per pass-1 block
#define BSH 8           // bucket = dst >> 8  (256 nodes/bucket)
#define MAXBK 512       // max coarse buckets (N <= 131072)

typedef _Float16 half8 __attribute__((ext_vector_type(8)));
typedef _Float16 half4v __attribute__((ext_vector_type(4)));
typedef float floatx4 __attribute__((ext_vector_type(4)));

// ---------------- bucket-level histogram (LDS-aggregated) ----------------
__global__ __launch_bounds__(256) void k_bhist(const int* __restrict__ dst,
                                               int* __restrict__ bcounts, int E, int NB) {
    __shared__ int lh[MAXBK];
    int tid = threadIdx.x;
    for (int b = tid; b < MAXBK; b += 256) lh[b] = 0;
    __syncthreads();
    int stride = gridDim.x * 256;
    for (int k = blockIdx.x * 256 + tid; k < E; k += stride)
        atomicAdd(&lh[dst[k] >> BSH], 1);
    __syncthreads();
    for (int b = tid; b < NB; b += 256) {
        int c = lh[b];
        if (c) atomicAdd(&bcounts[b], c);
    }
}

// ---------------- bucket scan: bucket_start, row_start[N], zero gcur ----------------
__global__ __launch_bounds__(512) void k_bscan(const int* __restrict__ bcounts,
                                               int* __restrict__ bucket_start,
                                               int* __restrict__ gcur,
                                               int* __restrict__ row_start_N,
                                               int NB, int E) {
    __shared__ int s[512];
    int t = threadIdx.x;
    int v = (t < NB) ? bcounts[t] : 0;
    s[t] = v;
    __syncthreads();
    for (int off = 1; off < 512; off <<= 1) {
        int x = (t >= off) ? s[t - off] : 0;
        __syncthreads();
        s[t] += x;
        __syncthreads();
    }
    if (t < NB) bucket_start[t] = s[t] - v;           // exclusive
    if (t == NB - 1) bucket_start[NB] = s[t];         // == E
    if (t == 0) *row_start_N = E;
    gcur[t] = 0;
}

// ---------------- pass 1: bucket-bin edges, direct global run-writes ----------------
// rec = { src | dlocal<<17 , w_bits }   (requires N <= 2^17, dlocal < 256)
__global__ __launch_bounds__(256) void k_pass1(const int* __restrict__ src,
                                               const int* __restrict__ dst,
                                               const float* __restrict__ w,
                                               const int* __restrict__ bucket_start,
                                               int* __restrict__ gcur,
                                               int2* __restrict__ out, int E, int NB) {
    __shared__ int lhist[MAXBK];
    __shared__ int lbase[MAXBK];
    __shared__ int lcur[MAXBK];
    int tid = threadIdx.x;
    int beg = blockIdx.x * CHUNK;
    int end = min(beg + CHUNK, E);

    for (int b = tid; b < MAXBK; b += 256) { lhist[b] = 0; lcur[b] = 0; }
    __syncthreads();
    for (int k = beg + tid; k < end; k += 256)
        atomicAdd(&lhist[dst[k] >> BSH], 1);
    __syncthreads();
    for (int b = tid; b < NB; b += 256) {
        int c = lhist[b];
        if (c) lbase[b] = bucket_start[b] + atomicAdd(&gcur[b], c);
    }
    __syncthreads();
    for (int k = beg + tid; k < end; k += 256) {
        int d = dst[k];
        int b = d >> BSH;
        int loc = atomicAdd(&lcur[b], 1);
        out[lbase[b] + loc] =
            make_int2(src[k] | ((d & ((1 << BSH) - 1)) << 17), __float_as_int(w[k]));
    }
}

// ---------------- pass 2: per-bucket count+scan+place, all LDS-local ----------------
__global__ __launch_bounds__(512) void k_pass2(const int2* __restrict__ bkt,
                                               const int* __restrict__ bucket_start,
                                               int* __restrict__ row_start,
                                               int2* __restrict__ edges, int N) {
    __shared__ int lhist[1 << BSH];
    __shared__ int loff[1 << BSH];
    __shared__ int lcur[1 << BSH];
    int tid = threadIdx.x;
    int b = blockIdx.x;
    int d0 = b << BSH;
    int sb = bucket_start[b], se = bucket_start[b + 1];

    if (tid < (1 << BSH)) lhist[tid] = 0;
    __syncthreads();
    // count per node
    for (int i = sb + tid; i < se; i += 512)
        atomicAdd(&lhist[(unsigned)bkt[i].x >> 17], 1);
    __syncthreads();
    // exclusive scan of 256 counters: one wave, 4 per lane
    if (tid < 64) {
        int base = tid * 4, v[4], s = 0;
        #pragma unroll
        for (int j = 0; j < 4; ++j) { v[j] = lhist[base + j]; s += v[j]; }
        int sc = s;
        #pragma unroll
        for (int off = 1; off < 64; off <<= 1) {
            int t = __shfl_up(sc, off, 64);
            if (tid >= off) sc += t;
        }
        int excl = sc - s;
        #pragma unroll
        for (int j = 0; j < 4; ++j) {
            loff[base + j] = excl; lcur[base + j] = excl; excl += v[j];
        }
    }
    __syncthreads();
    // coalesced row_start write
    if (tid < (1 << BSH)) {
        int d = d0 + tid;
        if (d < N) row_start[d] = sb + loff[tid];
    }
    // place edges (scatter confined to this bucket's 32KB region)
    for (int i = sb + tid; i < se; i += 512) {
        int2 r = bkt[i];
        int dl = (unsigned)r.x >> 17;
        int p = sb + atomicAdd(&lcur[dl], 1);
        edges[p] = make_int2(r.x & 0x1FFFF, r.y);
    }
}

// ---------------- casts ----------------
__global__ void k_cast_f2h(const float* __restrict__ in, _Float16* __restrict__ out, int n4) {
    int i = blockIdx.x * blockDim.x + threadIdx.x;
    if (i >= n4) return;
    float4 v = reinterpret_cast<const float4*>(in)[i];
    half4v h;
    h.x = (_Float16)v.x; h.y = (_Float16)v.y; h.z = (_Float16)v.z; h.w = (_Float16)v.w;
    reinterpret_cast<half4v*>(out)[i] = h;
}

__global__ void k_cast_wT(const float* __restrict__ W, _Float16* __restrict__ Wt) {
    int idx = blockIdx.x * blockDim.x + threadIdx.x;
    int n = idx >> 7, k = idx & 127;
    Wt[n * DD + k] = (_Float16)W[k * DD + n];
}

// ---------------- aggregation: one wave per dst; 16 lanes/row, 4 rows per gather ----
__global__ __launch_bounds__(256) void k_aggregate_h(const _Float16* __restrict__ x,
                                                     const int* __restrict__ row_start,
                                                     const int2* __restrict__ edges,
                                                     _Float16* __restrict__ out, int N) {
    int wid = (blockIdx.x * blockDim.x + threadIdx.x) >> 6;
    int lane = threadIdx.x & 63;
    if (wid >= N) return;
    int g = lane >> 4;    // edge group 0..3
    int sl = lane & 15;   // 16B chunk: cols sl*8 .. sl*8+7
    int beg = row_start[wid], end = row_start[wid + 1];
    float acc[8] = {0.f, 0.f, 0.f, 0.f, 0.f, 0.f, 0.f, 0.f};
    int i = beg;
    for (; i + 16 <= end; i += 16) {
        int2 e[4];
        #pragma unroll
        for (int u = 0; u < 4; ++u) e[u] = edges[i + u * 4 + g];
        half8 v[4];
        #pragma unroll
        for (int u = 0; u < 4; ++u)
            v[u] = *reinterpret_cast<const half8*>(x + (size_t)e[u].x * DD + sl * 8);
        #pragma unroll
        for (int u = 0; u < 4; ++u) {
            float wv = __int_as_float(e[u].y);
            #pragma unroll
            for (int j = 0; j < 8; ++j)
                acc[j] = fmaf((float)v[u][j], wv, acc[j]);
        }
    }
    for (; i < end; i += 4) {
        int rem = end - i;                 // >= 1
        int2 e = edges[i + min(g, rem - 1)];
        half8 v = *reinterpret_cast<const half8*>(x + (size_t)e.x * DD + sl * 8);
        float wv = (g < rem) ? __int_as_float(e.y) : 0.f;
        #pragma unroll
        for (int j = 0; j < 8; ++j)
            acc[j] = fmaf((float)v[j], wv, acc[j]);
    }
    #pragma unroll
    for (int j = 0; j < 8; ++j) {
        acc[j] += __shfl_xor(acc[j], 16, 64);
        acc[j] += __shfl_xor(acc[j], 32, 64);
    }
    if (g == 0) {
        half8 o;
        #pragma unroll
        for (int j = 0; j < 8; ++j) o[j] = (_Float16)acc[j];
        *reinterpret_cast<half8*>(out + (size_t)wid * DD + sl * 8) = o;
    }
}

// ---------------- MFMA GEMM: out = relu(A @ W + b) [+ resid], LDS-free ----------
__global__ __launch_bounds__(256) void k_gemm_mfma(const _Float16* __restrict__ A,
                                                   const _Float16* __restrict__ Wt,
                                                   const float* __restrict__ bias,
                                                   const _Float16* __restrict__ resid_h,
                                                   float* __restrict__ out_f32,
                                                   _Float16* __restrict__ out_f16,
                                                   int nrows) {
    int wave = threadIdx.x >> 6;
    int lane = threadIdx.x & 63;
    int row0 = blockIdx.x * 128 + wave * 32;
    int m = lane & 15;
    int q = lane >> 4;

    floatx4 acc[2][8];
    #pragma unroll
    for (int t = 0; t < 2; ++t)
        #pragma unroll
        for (int c = 0; c < 8; ++c)
            acc[t][c] = (floatx4){0.f, 0.f, 0.f, 0.f};

    #pragma unroll
    for (int ks = 0; ks < 4; ++ks) {
        int kbase = ks * 32 + q * 8;
        half8 a0 = *reinterpret_cast<const half8*>(A + (size_t)(row0 + m) * DD + kbase);
        half8 a1 = *reinterpret_cast<const half8*>(A + (size_t)(row0 + 16 + m) * DD + kbase);
        #pragma unroll
        for (int c = 0; c < 8; ++c) {
            half8 b = *reinterpret_cast<const half8*>(Wt + (size_t)(c * 16 + m) * DD + kbase);
            acc[0][c] = __builtin_amdgcn_mfma_f32_16x16x32_f16(a0, b, acc[0][c], 0, 0, 0);
            acc[1][c] = __builtin_amdgcn_mfma_f32_16x16x32_f16(a1, b, acc[1][c], 0, 0, 0);
        }
    }

    #pragma unroll
    for (int t = 0; t < 2; ++t) {
        #pragma unroll
        for (int c = 0; c < 8; ++c) {
            int col = c * 16 + m;
            float bv = bias[col];
            #pragma unroll
            for (int r = 0; r < 4; ++r) {
                int row = row0 + t * 16 + q * 4 + r;
                if (row < nrows) {
                    float v = acc[t][c][r] + bv;
                    v = v > 0.f ? v : 0.f;
                    if (resid_h) v += (float)resid_h[(size_t)row * DD + col];
                    if (out_f32) out_f32[(size_t)row * DD + col] = v;
                    if (out_f16) out_f16[(size_t)row * DD + col] = (_Float16)v;
                }
            }
        }
    }
}

// ---------------- per-subgraph mean pool + target residual ----------------
__global__ __launch_bounds__(128) void k_pool(const float* __restrict__ h,
                                              const int* __restrict__ target,
                                              const float* __restrict__ size_subg,
                                              float* __restrict__ pooled, int SZ) {
    int b = blockIdx.x;
    int d = threadIdx.x;
    const float* hp = h + (size_t)b * SZ * DD;
    float s = 0.f;
    for (int n = 0; n < SZ; ++n) s += hp[(size_t)n * DD + d];
    int t = target[b];
    float p = s / size_subg[b] + h[(size_t)t * DD + d];
    pooled[b * DD + d] = p;
}

// ---------------- final: relu(pooled @ Wp + bp), L2-normalize rows ----------------
__global__ __launch_bounds__(128) void k_final(const float* __restrict__ pooled,
                                               const float* __restrict__ Wp,
                                               const float* __restrict__ bp,
                                               float* __restrict__ out) {
    __shared__ float p[DD];
    __shared__ float wsum[2];
    int b = blockIdx.x;
    int c = threadIdx.x;
    p[c] = pooled[b * DD + c];
    __syncthreads();
    float acc = 0.f;
    #pragma unroll 4
    for (int k = 0; k < DD; ++k) acc = fmaf(p[k], Wp[k * DD + c], acc);
    float e = acc + bp[c];
    e = e > 0.f ? e : 0.f;
    float sq = e * e;
    #pragma unroll
    for (int off = 32; off > 0; off >>= 1) sq += __shfl_down(sq, off, 64);
    int lane = c & 63, w = c >> 6;
    if (lane == 0) wsum[w] = sq;
    __syncthreads();
    float norm = sqrtf(wsum[0] + wsum[1]);
    float scale = 1.f / fmaxf(norm, 1e-12f);
    out[b * DD + c] = e * scale;
}

extern "C" void kernel_launch(void* const* d_in, const int* in_sizes, int n_in,
                              void* d_out, int out_size, void* d_ws, size_t ws_size,
                              hipStream_t stream) {
    const float* feat      = (const float*)d_in[0];
    const float* edge_w    = (const float*)d_in[1];
    const float* W1        = (const float*)d_in[2];
    const float* b1        = (const float*)d_in[3];
    const float* W2        = (const float*)d_in[4];
    const float* b2        = (const float*)d_in[5];
    const float* Wp        = (const float*)d_in[6];
    const float* bp        = (const float*)d_in[7];
    const float* size_subg = (const float*)d_in[8];
    const int*   edge_src  = (const int*)d_in[9];
    const int*   edge_dst  = (const int*)d_in[10];
    const int*   target    = (const int*)d_in[12];

    const int N  = in_sizes[0] / DD;
    const int E  = in_sizes[1];
    const int B  = in_sizes[8];
    const int SZ = N / B;

    const int gemmBlocks = (N + 127) / 128;
    const int P = gemmBlocks * 128;
    const int NB = (N + (1 << BSH) - 1) >> BSH;   // coarse buckets (<= MAXBK)

    char* ws = (char*)d_ws;
    size_t off = 0;
    auto alloc = [&](size_t bytes) {
        void* p = ws + off;
        off += (bytes + 255) & ~(size_t)255;
        return p;
    };
    // region0: feat_h + agg1_h overlay; later reused as fp32 H
    char* region0   = (char*)alloc((size_t)N * DD * 4 + 40 * 1024);
    _Float16* feat_h = (_Float16*)region0;
    _Float16* agg1_h = (_Float16*)(region0 + (size_t)N * DD * 2);
    float*    H      = (float*)region0;
    _Float16* h1_h   = (_Float16*)alloc((size_t)P * DD * 2);
    _Float16* agg2_h = (_Float16*)alloc((size_t)P * DD * 2);  // also edges_bkt (pass1 out)
    int2*     edges_bkt = (int2*)agg2_h;                      // dead before agg2 is written
    _Float16* W1t    = (_Float16*)alloc((size_t)DD * DD * 2);
    _Float16* W2t    = (_Float16*)alloc((size_t)DD * DD * 2);
    int*   row_start = (int*)alloc(((size_t)N + 1) * 4);
    int*   bcounts      = (int*)alloc((size_t)MAXBK * 4);
    int*   bucket_start = (int*)alloc(((size_t)MAXBK + 1) * 4);
    int*   gcur         = (int*)alloc((size_t)MAXBK * 4);
    int2*  edges     = (int2*)alloc((size_t)E * 8);
    float* pooled    = (float*)alloc((size_t)B * DD * 4);

    // ---- CSR build: bucket hist -> bucket scan -> pass1 -> pass2 ----
    hipMemsetAsync(bcounts, 0, (size_t)MAXBK * 4, stream);
    k_bhist<<<256, 256, 0, stream>>>(edge_dst, bcounts, E, NB);
    k_bscan<<<1, 512, 0, stream>>>(bcounts, bucket_start, gcur, row_start + N, NB, E);
    int p1Blocks = (E + CHUNK - 1) / CHUNK;
    k_pass1<<<p1Blocks, 256, 0, stream>>>(edge_src, edge_dst, edge_w, bucket_start,
                                          gcur, edges_bkt, E, NB);
    k_pass2<<<NB, 512, 0, stream>>>(edges_bkt, bucket_start, row_start, edges, N);

    // ---- casts ----
    int n4 = N * DD / 4;
    k_cast_f2h<<<(n4 + 255) / 256, 256, 0, stream>>>(feat, feat_h, n4);
    k_cast_wT<<<64, 256, 0, stream>>>(W1, W1t);
    k_cast_wT<<<64, 256, 0, stream>>>(W2, W2t);

    int aggBlocks = (N * 64 + 255) / 256;   // one wave per node

    // layer 1
    k_aggregate_h<<<aggBlocks, 256, 0, stream>>>(feat_h, row_start, edges, agg1_h, N);
    k_gemm_mfma<<<gemmBlocks, 256, 0, stream>>>(agg1_h, W1t, b1, nullptr,
                                                nullptr, h1_h, N);
    // layer 2
    k_aggregate_h<<<aggBlocks, 256, 0, stream>>>(h1_h, row_start, edges, agg2_h, N);
    k_gemm_mfma<<<gemmBlocks, 256, 0, stream>>>(agg2_h, W2t, b2, h1_h,
                                                H, nullptr, N);
    // pool + final
    k_pool<<<B, 128, 0, stream>>>(H, target, size_subg, pooled, SZ);
    k_final<<<B, 128, 0, stream>>>(pooled, Wp, bp, (float*)d_out);
}

// Round 7
// 428.204 us; speedup vs baseline: 1.7940x; 1.0696x over previous
//
#include <hip/hip_runtime.h>

#define DD 128
#define CHUNK 4096      // edges per pass-1 block
#define BSH 8           // bucket = dst >> 8  (256 nodes/bucket)
#define MAXBK 512       // max coarse buckets (N <= 131072)

typedef _Float16 half8 __attribute__((ext_vector_type(8)));
typedef _Float16 half4v __attribute__((ext_vector_type(4)));
typedef float floatx4 __attribute__((ext_vector_type(4)));

// ---------------- bucket-level histogram (LDS-aggregated) ----------------
__global__ __launch_bounds__(256) void k_bhist(const int* __restrict__ dst,
                                               int* __restrict__ bcounts, int E, int NB) {
    __shared__ int lh[MAXBK];
    int tid = threadIdx.x;
    for (int b = tid; b < MAXBK; b += 256) lh[b] = 0;
    __syncthreads();
    int stride = gridDim.x * 256;
    for (int k = blockIdx.x * 256 + tid; k < E; k += stride)
        atomicAdd(&lh[dst[k] >> BSH], 1);
    __syncthreads();
    for (int b = tid; b < NB; b += 256) {
        int c = lh[b];
        if (c) atomicAdd(&bcounts[b], c);
    }
}

// ---------------- bucket scan: bucket_start, row_start[N], zero gcur ----------------
__global__ __launch_bounds__(512) void k_bscan(const int* __restrict__ bcounts,
                                               int* __restrict__ bucket_start,
                                               int* __restrict__ gcur,
                                               int* __restrict__ row_start_N,
                                               int NB, int E) {
    __shared__ int s[512];
    int t = threadIdx.x;
    int v = (t < NB) ? bcounts[t] : 0;
    s[t] = v;
    __syncthreads();
    for (int off = 1; off < 512; off <<= 1) {
        int x = (t >= off) ? s[t - off] : 0;
        __syncthreads();
        s[t] += x;
        __syncthreads();
    }
    if (t < NB) bucket_start[t] = s[t] - v;           // exclusive
    if (t == NB - 1) bucket_start[NB] = s[t];         // == E
    if (t == 0) *row_start_N = E;
    gcur[t] = 0;
}

// ---------------- pass 1: bucket-bin edges, direct global run-writes ----------------
// rec = { src | dlocal<<17 , w_bits }   (requires N <= 2^17, dlocal < 256)
__global__ __launch_bounds__(256) void k_pass1(const int* __restrict__ src,
                                               const int* __restrict__ dst,
                                               const float* __restrict__ w,
                                               const int* __restrict__ bucket_start,
                                               int* __restrict__ gcur,
                                               int2* __restrict__ out, int E, int NB) {
    __shared__ int lhist[MAXBK];
    __shared__ int lbase[MAXBK];
    __shared__ int lcur[MAXBK];
    int tid = threadIdx.x;
    int beg = blockIdx.x * CHUNK;
    int end = min(beg + CHUNK, E);

    for (int b = tid; b < MAXBK; b += 256) { lhist[b] = 0; lcur[b] = 0; }
    __syncthreads();
    for (int k = beg + tid; k < end; k += 256)
        atomicAdd(&lhist[dst[k] >> BSH], 1);
    __syncthreads();
    for (int b = tid; b < NB; b += 256) {
        int c = lhist[b];
        if (c) lbase[b] = bucket_start[b] + atomicAdd(&gcur[b], c);
    }
    __syncthreads();
    for (int k = beg + tid; k < end; k += 256) {
        int d = dst[k];
        int b = d >> BSH;
        int loc = atomicAdd(&lcur[b], 1);
        out[lbase[b] + loc] =
            make_int2(src[k] | ((d & ((1 << BSH) - 1)) << 17), __float_as_int(w[k]));
    }
}

// ---------------- pass 2: per-bucket count+scan+place, all LDS-local ----------------
__global__ __launch_bounds__(512) void k_pass2(const int2* __restrict__ bkt,
                                               const int* __restrict__ bucket_start,
                                               int* __restrict__ row_start,
                                               int2* __restrict__ edges, int N) {
    __shared__ int lhist[1 << BSH];
    __shared__ int loff[1 << BSH];
    __shared__ int lcur[1 << BSH];
    int tid = threadIdx.x;
    int b = blockIdx.x;
    int d0 = b << BSH;
    int sb = bucket_start[b], se = bucket_start[b + 1];

    if (tid < (1 << BSH)) lhist[tid] = 0;
    __syncthreads();
    for (int i = sb + tid; i < se; i += 512)
        atomicAdd(&lhist[(unsigned)bkt[i].x >> 17], 1);
    __syncthreads();
    if (tid < 64) {
        int base = tid * 4, v[4], s = 0;
        #pragma unroll
        for (int j = 0; j < 4; ++j) { v[j] = lhist[base + j]; s += v[j]; }
        int sc = s;
        #pragma unroll
        for (int off = 1; off < 64; off <<= 1) {
            int t = __shfl_up(sc, off, 64);
            if (tid >= off) sc += t;
        }
        int excl = sc - s;
        #pragma unroll
        for (int j = 0; j < 4; ++j) {
            loff[base + j] = excl; lcur[base + j] = excl; excl += v[j];
        }
    }
    __syncthreads();
    if (tid < (1 << BSH)) {
        int d = d0 + tid;
        if (d < N) row_start[d] = sb + loff[tid];
    }
    for (int i = sb + tid; i < se; i += 512) {
        int2 r = bkt[i];
        int dl = (unsigned)r.x >> 17;
        int p = sb + atomicAdd(&lcur[dl], 1);
        edges[p] = make_int2(r.x & 0x1FFFF, r.y);
    }
}

// ---------------- casts ----------------
__global__ void k_cast_f2h(const float* __restrict__ in, _Float16* __restrict__ out, int n4) {
    int i = blockIdx.x * blockDim.x + threadIdx.x;
    if (i >= n4) return;
    float4 v = reinterpret_cast<const float4*>(in)[i];
    half4v h;
    h.x = (_Float16)v.x; h.y = (_Float16)v.y; h.z = (_Float16)v.z; h.w = (_Float16)v.w;
    reinterpret_cast<half4v*>(out)[i] = h;
}

__global__ void k_cast_wT(const float* __restrict__ W, _Float16* __restrict__ Wt) {
    int idx = blockIdx.x * blockDim.x + threadIdx.x;
    int n = idx >> 7, k = idx & 127;
    Wt[n * DD + k] = (_Float16)W[k * DD + n];
}

// ---------------- aggregation: one wave per dst; 16 lanes/row, 4 rows per gather ----
__global__ __launch_bounds__(256) void k_aggregate_h(const _Float16* __restrict__ x,
                                                     const int* __restrict__ row_start,
                                                     const int2* __restrict__ edges,
                                                     _Float16* __restrict__ out, int N) {
    int wid = (blockIdx.x * blockDim.x + threadIdx.x) >> 6;
    int lane = threadIdx.x & 63;
    if (wid >= N) return;
    int g = lane >> 4;    // edge group 0..3
    int sl = lane & 15;   // 16B chunk: cols sl*8 .. sl*8+7
    int beg = row_start[wid], end = row_start[wid + 1];
    float acc[8] = {0.f, 0.f, 0.f, 0.f, 0.f, 0.f, 0.f, 0.f};
    int i = beg;
    for (; i + 16 <= end; i += 16) {
        int2 e[4];
        #pragma unroll
        for (int u = 0; u < 4; ++u) e[u] = edges[i + u * 4 + g];
        half8 v[4];
        #pragma unroll
        for (int u = 0; u < 4; ++u)
            v[u] = *reinterpret_cast<const half8*>(x + (size_t)e[u].x * DD + sl * 8);
        #pragma unroll
        for (int u = 0; u < 4; ++u) {
            float wv = __int_as_float(e[u].y);
            #pragma unroll
            for (int j = 0; j < 8; ++j)
                acc[j] = fmaf((float)v[u][j], wv, acc[j]);
        }
    }
    for (; i < end; i += 4) {
        int rem = end - i;                 // >= 1
        int2 e = edges[i + min(g, rem - 1)];
        half8 v = *reinterpret_cast<const half8*>(x + (size_t)e.x * DD + sl * 8);
        float wv = (g < rem) ? __int_as_float(e.y) : 0.f;
        #pragma unroll
        for (int j = 0; j < 8; ++j)
            acc[j] = fmaf((float)v[j], wv, acc[j]);
    }
    #pragma unroll
    for (int j = 0; j < 8; ++j) {
        acc[j] += __shfl_xor(acc[j], 16, 64);
        acc[j] += __shfl_xor(acc[j], 32, 64);
    }
    if (g == 0) {
        half8 o;
        #pragma unroll
        for (int j = 0; j < 8; ++j) o[j] = (_Float16)acc[j];
        *reinterpret_cast<half8*>(out + (size_t)wid * DD + sl * 8) = o;
    }
}

// ---------------- MFMA GEMM (operand-swapped): out = relu(A @ W + b) [+ resid] ----
// mfma(Wt_frag, A_frag, acc): D col(lane&15) = A-row m, D row(q*4+r) = W out-col.
// => thread holds out[row0 + t*16 + m][c*16 + q*4 .. +3]  -> float4/half4 epilogue.
__global__ __launch_bounds__(256) void k_gemm_mfma(const _Float16* __restrict__ A,
                                                   const _Float16* __restrict__ Wt,
                                                   const float* __restrict__ bias,
                                                   const _Float16* __restrict__ resid_h,
                                                   float* __restrict__ out_f32,
                                                   _Float16* __restrict__ out_f16,
                                                   int nrows) {
    int wave = threadIdx.x >> 6;
    int lane = threadIdx.x & 63;
    int row0 = blockIdx.x * 128 + wave * 32;
    int m = lane & 15;
    int q = lane >> 4;

    floatx4 acc[2][8];
    #pragma unroll
    for (int t = 0; t < 2; ++t)
        #pragma unroll
        for (int c = 0; c < 8; ++c)
            acc[t][c] = (floatx4){0.f, 0.f, 0.f, 0.f};

    #pragma unroll
    for (int ks = 0; ks < 4; ++ks) {
        int kbase = ks * 32 + q * 8;
        half8 a0 = *reinterpret_cast<const half8*>(A + (size_t)(row0 + m) * DD + kbase);
        half8 a1 = *reinterpret_cast<const half8*>(A + (size_t)(row0 + 16 + m) * DD + kbase);
        #pragma unroll
        for (int c = 0; c < 8; ++c) {
            half8 b = *reinterpret_cast<const half8*>(Wt + (size_t)(c * 16 + m) * DD + kbase);
            acc[0][c] = __builtin_amdgcn_mfma_f32_16x16x32_f16(b, a0, acc[0][c], 0, 0, 0);
            acc[1][c] = __builtin_amdgcn_mfma_f32_16x16x32_f16(b, a1, acc[1][c], 0, 0, 0);
        }
    }

    #pragma unroll
    for (int t = 0; t < 2; ++t) {
        int row = row0 + t * 16 + m;
        if (row >= nrows) continue;
        size_t rb = (size_t)row * DD;
        #pragma unroll
        for (int c = 0; c < 8; ++c) {
            int col = c * 16 + q * 4;
            float4 bv = *reinterpret_cast<const float4*>(&bias[col]);
            float o[4] = {acc[t][c][0] + bv.x, acc[t][c][1] + bv.y,
                          acc[t][c][2] + bv.z, acc[t][c][3] + bv.w};
            #pragma unroll
            for (int r = 0; r < 4; ++r) o[r] = o[r] > 0.f ? o[r] : 0.f;
            if (resid_h) {
                half4v r4 = *reinterpret_cast<const half4v*>(&resid_h[rb + col]);
                #pragma unroll
                for (int r = 0; r < 4; ++r) o[r] += (float)r4[r];
            }
            if (out_f32)
                *reinterpret_cast<float4*>(&out_f32[rb + col]) =
                    make_float4(o[0], o[1], o[2], o[3]);
            if (out_f16) {
                half4v h;
                #pragma unroll
                for (int r = 0; r < 4; ++r) h[r] = (_Float16)o[r];
                *reinterpret_cast<half4v*>(&out_f16[rb + col]) = h;
            }
        }
    }
}

// ---------------- per-subgraph mean pool + target residual ----------------
__global__ __launch_bounds__(128) void k_pool(const float* __restrict__ h,
                                              const int* __restrict__ target,
                                              const float* __restrict__ size_subg,
                                              float* __restrict__ pooled, int SZ) {
    int b = blockIdx.x;
    int d = threadIdx.x;
    const float* hp = h + (size_t)b * SZ * DD;
    float s = 0.f;
    for (int n = 0; n < SZ; ++n) s += hp[(size_t)n * DD + d];
    int t = target[b];
    float p = s / size_subg[b] + h[(size_t)t * DD + d];
    pooled[b * DD + d] = p;
}

// ---------------- final: relu(pooled @ Wp + bp), L2-normalize rows ----------------
__global__ __launch_bounds__(128) void k_final(const float* __restrict__ pooled,
                                               const float* __restrict__ Wp,
                                               const float* __restrict__ bp,
                                               float* __restrict__ out) {
    __shared__ float p[DD];
    __shared__ float wsum[2];
    int b = blockIdx.x;
    int c = threadIdx.x;
    p[c] = pooled[b * DD + c];
    __syncthreads();
    float acc = 0.f;
    #pragma unroll 4
    for (int k = 0; k < DD; ++k) acc = fmaf(p[k], Wp[k * DD + c], acc);
    float e = acc + bp[c];
    e = e > 0.f ? e : 0.f;
    float sq = e * e;
    #pragma unroll
    for (int off = 32; off > 0; off >>= 1) sq += __shfl_down(sq, off, 64);
    int lane = c & 63, w = c >> 6;
    if (lane == 0) wsum[w] = sq;
    __syncthreads();
    float norm = sqrtf(wsum[0] + wsum[1]);
    float scale = 1.f / fmaxf(norm, 1e-12f);
    out[b * DD + c] = e * scale;
}

extern "C" void kernel_launch(void* const* d_in, const int* in_sizes, int n_in,
                              void* d_out, int out_size, void* d_ws, size_t ws_size,
                              hipStream_t stream) {
    const float* feat      = (const float*)d_in[0];
    const float* edge_w    = (const float*)d_in[1];
    const float* W1        = (const float*)d_in[2];
    const float* b1        = (const float*)d_in[3];
    const float* W2        = (const float*)d_in[4];
    const float* b2        = (const float*)d_in[5];
    const float* Wp        = (const float*)d_in[6];
    const float* bp        = (const float*)d_in[7];
    const float* size_subg = (const float*)d_in[8];
    const int*   edge_src  = (const int*)d_in[9];
    const int*   edge_dst  = (const int*)d_in[10];
    const int*   target    = (const int*)d_in[12];

    const int N  = in_sizes[0] / DD;
    const int E  = in_sizes[1];
    const int B  = in_sizes[8];
    const int SZ = N / B;

    const int gemmBlocks = (N + 127) / 128;
    const int P = gemmBlocks * 128;
    const int NB = (N + (1 << BSH) - 1) >> BSH;   // coarse buckets (<= MAXBK)

    char* ws = (char*)d_ws;
    size_t off = 0;
    auto alloc = [&](size_t bytes) {
        void* p = ws + off;
        off += (bytes + 255) & ~(size_t)255;
        return p;
    };
    // region0: feat_h + agg1_h overlay; later reused as fp32 H
    char* region0   = (char*)alloc((size_t)N * DD * 4 + 40 * 1024);
    _Float16* feat_h = (_Float16*)region0;
    _Float16* agg1_h = (_Float16*)(region0 + (size_t)N * DD * 2);
    float*    H      = (float*)region0;
    _Float16* h1_h   = (_Float16*)alloc((size_t)P * DD * 2);
    _Float16* agg2_h = (_Float16*)alloc((size_t)P * DD * 2);  // also edges_bkt (pass1 out)
    int2*     edges_bkt = (int2*)agg2_h;                      // dead before agg2 is written
    _Float16* W1t    = (_Float16*)alloc((size_t)DD * DD * 2);
    _Float16* W2t    = (_Float16*)alloc((size_t)DD * DD * 2);
    int*   row_start = (int*)alloc(((size_t)N + 1) * 4);
    int*   bcounts      = (int*)alloc((size_t)MAXBK * 4);
    int*   bucket_start = (int*)alloc(((size_t)MAXBK + 1) * 4);
    int*   gcur         = (int*)alloc((size_t)MAXBK * 4);
    int2*  edges     = (int2*)alloc((size_t)E * 8);
    float* pooled    = (float*)alloc((size_t)B * DD * 4);

    // ---- CSR build: bucket hist -> bucket scan -> pass1 -> pass2 ----
    hipMemsetAsync(bcounts, 0, (size_t)MAXBK * 4, stream);
    k_bhist<<<256, 256, 0, stream>>>(edge_dst, bcounts, E, NB);
    k_bscan<<<1, 512, 0, stream>>>(bcounts, bucket_start, gcur, row_start + N, NB, E);
    int p1Blocks = (E + CHUNK - 1) / CHUNK;
    k_pass1<<<p1Blocks, 256, 0, stream>>>(edge_src, edge_dst, edge_w, bucket_start,
                                          gcur, edges_bkt, E, NB);
    k_pass2<<<NB, 512, 0, stream>>>(edges_bkt, bucket_start, row_start, edges, N);

    // ---- casts ----
    int n4 = N * DD / 4;
    k_cast_f2h<<<(n4 + 255) / 256, 256, 0, stream>>>(feat, feat_h, n4);
    k_cast_wT<<<64, 256, 0, stream>>>(W1, W1t);
    k_cast_wT<<<64, 256, 0, stream>>>(W2, W2t);

    int aggBlocks = (N * 64 + 255) / 256;   // one wave per node

    // layer 1
    k_aggregate_h<<<aggBlocks, 256, 0, stream>>>(feat_h, row_start, edges, agg1_h, N);
    k_gemm_mfma<<<gemmBlocks, 256, 0, stream>>>(agg1_h, W1t, b1, nullptr,
                                                nullptr, h1_h, N);
    // layer 2
    k_aggregate_h<<<aggBlocks, 256, 0, stream>>>(h1_h, row_start, edges, agg2_h, N);
    k_gemm_mfma<<<gemmBlocks, 256, 0, stream>>>(agg2_h, W2t, b2, h1_h,
                                                H, nullptr, N);
    // pool + final
    k_pool<<<B, 128, 0, stream>>>(H, target, size_subg, pooled, SZ);
    k_final<<<B, 128, 0, stream>>>(pooled, Wp, bp, (float*)d_out);
}